// Round 6
// baseline (269.676 us; speedup 1.0000x reference)
//
#include <hip/hip_runtime.h>

typedef __attribute__((ext_vector_type(8))) short bf16x8;
typedef __attribute__((ext_vector_type(4))) float f32x4;

constexpr int BROWS  = 131072;
constexpr int DDIM   = 128;
constexpr int NTILES = BROWS / 16;   // 8192 row-tiles of 16
constexpr int GRID   = 1024;
constexpr int TPB    = NTILES / GRID; // 8 tiles per block

__device__ __forceinline__ short to_bf16(float f) {
    unsigned u = __builtin_bit_cast(unsigned, f);
    u = (u + 0x7FFFu + ((u >> 16) & 1u)) >> 16;   // RTNE
    return (short)u;
}

__device__ __forceinline__ bf16x8 cvt8(f32x4 lo, f32x4 hi) {
    bf16x8 r;
#pragma unroll
    for (int i = 0; i < 4; ++i) { r[i] = to_bf16(lo[i]); r[i + 4] = to_bf16(hi[i]); }
    return r;
}

// 512-thread block = 8 waves sharing one 16-row state tile (single-pass reads).
// Wave w owns 32 output cols: plane cls = w>>2, colbase = (w&3)*32.
// Operand-swapped MFMA (A = W-frag, B = state-frag):
//   D row(lq*4+r) = output col, col(l16) = b-row -> lane stores f32x4 of 4
//   consecutive cols at one b-row; 2 nontemporal dwordx4 stores per tile.
__global__ void __launch_bounds__(512, 4)
lfm_kernel(const float* __restrict__ state, const float* __restrict__ W,
           const float* __restrict__ bias, float* __restrict__ out) {
    const int lane = threadIdx.x & 63;
    const int wave = threadIdx.x >> 6;       // 0..7
    const int l16  = lane & 15;
    const int lq   = lane >> 4;

    const int cls     = wave >> 2;           // 0 -> delta, 1 -> var
    const int colbase = (wave & 3) * 32;     // cols within the plane

    // ---- W fragments + bias (once per block; W/bias are L2-hot) ----
    bf16x8 wfrag[2][4];
    f32x4  bias4[2];
#pragma unroll
    for (int ct = 0; ct < 2; ++ct) {
        const int n = colbase + ct * 16 + l16;
        const float* wrow = W + n * 256 + cls * 128;   // W[n][cls][*]
#pragma unroll
        for (int ks = 0; ks < 4; ++ks) {
            f32x4 lo = *reinterpret_cast<const f32x4*>(wrow + ks * 32 + lq * 8);
            f32x4 hi = *reinterpret_cast<const f32x4*>(wrow + ks * 32 + lq * 8 + 4);
            wfrag[ct][ks] = cvt8(lo, hi);
        }
        const int c0 = colbase + ct * 16 + lq * 4;
#pragma unroll
        for (int r = 0; r < 4; ++r)
            bias4[ct][r] = bias[(c0 + r) * 2 + cls];
    }

    float* oplane = out + (size_t)cls * BROWS * 128;

#define LOADT(BUF, T) { \
    const float* srow = state + ((size_t)((T) * 16 + l16)) * DDIM + lq * 8; \
    _Pragma("unroll") \
    for (int ks = 0; ks < 4; ++ks) { \
        BUF[2 * ks]     = *reinterpret_cast<const f32x4*>(srow + ks * 32); \
        BUF[2 * ks + 1] = *reinterpret_cast<const f32x4*>(srow + ks * 32 + 4); \
    } }

#define COMPUTE(BUF, T) { \
    f32x4 acc0 = bias4[0], acc1 = bias4[1]; \
    _Pragma("unroll") \
    for (int ks = 0; ks < 4; ++ks) { \
        bf16x8 af = cvt8(BUF[2 * ks], BUF[2 * ks + 1]); \
        acc0 = __builtin_amdgcn_mfma_f32_16x16x32_bf16(wfrag[0][ks], af, acc0, 0, 0, 0); \
        acc1 = __builtin_amdgcn_mfma_f32_16x16x32_bf16(wfrag[1][ks], af, acc1, 0, 0, 0); \
    } \
    float* orow = oplane + ((size_t)((T) * 16 + l16)) * 128; \
    __builtin_nontemporal_store(acc0, reinterpret_cast<f32x4*>(orow + colbase + lq * 4)); \
    __builtin_nontemporal_store(acc1, reinterpret_cast<f32x4*>(orow + colbase + 16 + lq * 4)); }

    // depth-2 register pipeline over this block's 8 tiles (stride = GRID)
    const int tb = blockIdx.x;
    f32x4 rawA[8], rawB[8];
    LOADT(rawA, tb)
    LOADT(rawB, (tb + GRID))
    COMPUTE(rawA, tb)                 LOADT(rawA, (tb + 2 * GRID))
    COMPUTE(rawB, (tb + GRID))        LOADT(rawB, (tb + 3 * GRID))
    COMPUTE(rawA, (tb + 2 * GRID))    LOADT(rawA, (tb + 4 * GRID))
    COMPUTE(rawB, (tb + 3 * GRID))    LOADT(rawB, (tb + 5 * GRID))
    COMPUTE(rawA, (tb + 4 * GRID))    LOADT(rawA, (tb + 6 * GRID))
    COMPUTE(rawB, (tb + 5 * GRID))    LOADT(rawB, (tb + 7 * GRID))
    COMPUTE(rawA, (tb + 6 * GRID))
    COMPUTE(rawB, (tb + 7 * GRID))
#undef LOADT
#undef COMPUTE
}

extern "C" void kernel_launch(void* const* d_in, const int* in_sizes, int n_in,
                              void* d_out, int out_size, void* d_ws, size_t ws_size,
                              hipStream_t stream) {
    const float* state = (const float*)d_in[0];
    const float* W     = (const float*)d_in[1];
    const float* bias  = (const float*)d_in[2];
    float* out = (float*)d_out;
    hipLaunchKernelGGL(lfm_kernel, dim3(GRID), dim3(512), 0, stream,
                       state, W, bias, out);
}